// Round 20
// baseline (243.747 us; speedup 1.0000x reference)
//
#include <hip/hip_runtime.h>

typedef __bf16 bf16;
typedef __attribute__((ext_vector_type(8))) __bf16 bf16x8;
typedef __attribute__((ext_vector_type(4))) __bf16 bf16x4;
typedef __attribute__((ext_vector_type(4))) float f32x4;

#define MFMA16(a, b, c) __builtin_amdgcn_mfma_f32_16x16x32_bf16((a), (b), (c), 0, 0, 0)

typedef __attribute__((address_space(1))) const void* gas_t;
typedef __attribute__((address_space(3))) void* las_t;
#define GLOAD_LDS16(g, l) \
    __builtin_amdgcn_global_load_lds((gas_t)(g), (las_t)(l), 16, 0, 0)

__device__ __forceinline__ unsigned pack2(float a, float b) {
    unsigned short ua = __builtin_bit_cast(unsigned short, (bf16)a);
    unsigned short ub = __builtin_bit_cast(unsigned short, (bf16)b);
    return ((unsigned)ub << 16) | (unsigned)ua;
}

// ---------------------------------------------------------------------------
// Fused transpose+cvt of all four weights: W[K][N] fp32 -> Wt[N][K] bf16.
// ---------------------------------------------------------------------------
__global__ void transpose_cvt4(const float* __restrict__ Wq,
                               const float* __restrict__ Wo,
                               const float* __restrict__ Wk,
                               const float* __restrict__ Wv,
                               bf16* __restrict__ WqT, bf16* __restrict__ WoT,
                               bf16* __restrict__ WkT, bf16* __restrict__ WvT) {
    __shared__ bf16 tile[32][33];
    int z = blockIdx.z;
    const float* W = (z == 0) ? Wq : (z == 1) ? Wo : (z == 2) ? Wk : Wv;
    bf16* Wt = (z == 0) ? WqT : (z == 1) ? WoT : (z == 2) ? WkT : WvT;
    int N = (z < 2) ? 2048 : 512;
    const int K = 2048;
    int n0 = blockIdx.x * 32;
    if (n0 >= N) return;
    int k0 = blockIdx.y * 32;
    int tx = threadIdx.x, ty = threadIdx.y;  // 32 x 8
#pragma unroll
    for (int j = 0; j < 4; ++j)
        tile[ty + j * 8][tx] = (bf16)W[(size_t)(k0 + ty + j * 8) * N + n0 + tx];
    __syncthreads();
#pragma unroll
    for (int j = 0; j < 4; ++j)
        Wt[(size_t)(n0 + ty + j * 8) * K + k0 + tx] = tile[tx][ty + j * 8];
}

// ---------------------------------------------------------------------------
// Q projection, wide-N tiles: 64(M) x 256(N), BK=64, grid (8,64).
// ---------------------------------------------------------------------------
__global__ __launch_bounds__(256) void gemm_q(
    const float* __restrict__ A, const bf16* __restrict__ Bt,
    bf16* __restrict__ Qp, const float* __restrict__ cosb,
    const float* __restrict__ sinb, float qscale) {
    const int Kk = 2048, Nn = 2048;
    __shared__ bf16 As[64 * 64];
    __shared__ bf16 Bs[256 * 64];
    int tid = threadIdx.x;
    int lane = tid & 63, wid = tid >> 6;
    int lr = lane & 15, lg = lane >> 4;
    int m0 = blockIdx.y * 64, n0 = blockIdx.x * 256;

    int srow = lane >> 3;
    int scol = ((lane & 7) ^ srow) << 3;
    const bf16* Bbase = Bt + (size_t)(n0 + wid * 64 + srow) * Kk + scol;

    int fragBr = wid * 64 + lr;
    int swz = lr & 7;

    f32x4 acc[4][4] = {};

    for (int kt = 0; kt < 32; ++kt) {
        int k0 = kt << 6;
#pragma unroll
        for (int i = 0; i < 4; ++i) {
            int slot = tid + i * 256;
            int row = slot >> 4, c4 = (slot & 15) << 2;
            f32x4 v = *reinterpret_cast<const f32x4*>(
                A + (size_t)(m0 + row) * Kk + k0 + c4);
            bf16x4 h;
            h[0] = (bf16)v[0]; h[1] = (bf16)v[1];
            h[2] = (bf16)v[2]; h[3] = (bf16)v[3];
            int blk = (c4 >> 3) ^ (row & 7);
            *reinterpret_cast<bf16x4*>(&As[row * 64 + (blk << 3) + (c4 & 7)]) = h;
        }
#pragma unroll
        for (int i = 0; i < 8; ++i)
            GLOAD_LDS16(Bbase + (size_t)(i * 8) * Kk + k0,
                        &Bs[(wid * 8 + i) * 512]);
        __syncthreads();
#pragma unroll
        for (int kk = 0; kk < 2; ++kk) {
            int colOff = ((((kk << 2) | lg) ^ swz) << 3);
            bf16x8 af[4], bfr[4];
#pragma unroll
            for (int mi = 0; mi < 4; ++mi)
                af[mi] = *reinterpret_cast<const bf16x8*>(
                    &As[(mi * 16 + lr) * 64 + colOff]);
#pragma unroll
            for (int ni = 0; ni < 4; ++ni)
                bfr[ni] = *reinterpret_cast<const bf16x8*>(
                    &Bs[(fragBr + ni * 16) * 64 + colOff]);
#pragma unroll
            for (int mi = 0; mi < 4; ++mi)
#pragma unroll
                for (int ni = 0; ni < 4; ++ni)
                    acc[mi][ni] = MFMA16(af[mi], bfr[ni], acc[mi][ni]);
        }
        __syncthreads();
    }

    int n_base = n0 + wid * 64;
#pragma unroll
    for (int mi = 0; mi < 4; ++mi) {
#pragma unroll
        for (int ni = 0; ni < 4; ++ni) {
            f32x4 v = acc[mi][ni];
            int gn = n_base + ni * 16 + lr;
            int d = gn & 127, p = d >> 1;
            bool ev = ((d & 1) == 0);
#pragma unroll
            for (int r = 0; r < 4; ++r) {
                int gm = m0 + mi * 16 + lg * 4 + r;
                int s = gm & 2047;
                float cc = cosb[s * 64 + p];
                float ss = sinb[s * 64 + p];
                float oth = __shfl_xor(v[r], 1);
                v[r] = (ev ? (v[r] * cc - oth * ss)
                           : (oth * ss + v[r] * cc)) * qscale;
            }
#pragma unroll
            for (int r = 0; r < 4; ++r)
                Qp[(size_t)(m0 + mi * 16 + lg * 4 + r) * Nn + gn] =
                    (bf16)v[r];
        }
    }
}

// ---------------------------------------------------------------------------
// Fused K+V projection, M-split tiles: 64(M) x 128(N). grid (4, 64, 2).
// ---------------------------------------------------------------------------
__global__ __launch_bounds__(256) void gemm_kv(
    const float* __restrict__ kin, const float* __restrict__ vin,
    const bf16* __restrict__ WkT, const bf16* __restrict__ WvT,
    bf16* __restrict__ Kt, bf16* __restrict__ Vt,
    const float* __restrict__ cosb, const float* __restrict__ sinb) {
    const int Kk = 2048;
    __shared__ bf16 As[64 * 64];
    __shared__ bf16 Bs[128 * 64];
    bool isK = (blockIdx.z == 0);
    const float* A = isK ? kin : vin;
    const bf16* Bt = isK ? WkT : WvT;

    int tid = threadIdx.x;
    int lane = tid & 63, wid = tid >> 6;
    int lr = lane & 15, lg = lane >> 4;
    int m0 = blockIdx.y * 64, n0 = blockIdx.x * 128;
    int wr = wid >> 1, wc = wid & 1;

    int srow = lane >> 3;
    int scol = ((lane & 7) ^ srow) << 3;
    const bf16* Bbase = Bt + (size_t)(n0 + wid * 32 + srow) * Kk + scol;

    int fragAr = wr * 32 + lr;
    int fragBr = wc * 64 + lr;
    int swz = lr & 7;

    f32x4 acc[2][4] = {};

    for (int kt = 0; kt < 32; ++kt) {
        int k0 = kt << 6;
#pragma unroll
        for (int i = 0; i < 4; ++i) {
            int slot = tid + i * 256;
            int row = slot >> 4, c4 = (slot & 15) << 2;
            f32x4 v = *reinterpret_cast<const f32x4*>(
                A + (size_t)(m0 + row) * Kk + k0 + c4);
            bf16x4 h;
            h[0] = (bf16)v[0]; h[1] = (bf16)v[1];
            h[2] = (bf16)v[2]; h[3] = (bf16)v[3];
            int blk = (c4 >> 3) ^ (row & 7);
            *reinterpret_cast<bf16x4*>(&As[row * 64 + (blk << 3) + (c4 & 7)]) = h;
        }
#pragma unroll
        for (int i = 0; i < 4; ++i)
            GLOAD_LDS16(Bbase + (size_t)(i * 8) * Kk + k0,
                        &Bs[(wid * 4 + i) * 512]);
        __syncthreads();
#pragma unroll
        for (int kk = 0; kk < 2; ++kk) {
            int colOff = ((((kk << 2) | lg) ^ swz) << 3);
            bf16x8 af[2], bfr[4];
#pragma unroll
            for (int mi = 0; mi < 2; ++mi)
                af[mi] = *reinterpret_cast<const bf16x8*>(
                    &As[(fragAr + mi * 16) * 64 + colOff]);
#pragma unroll
            for (int ni = 0; ni < 4; ++ni)
                bfr[ni] = *reinterpret_cast<const bf16x8*>(
                    &Bs[(fragBr + ni * 16) * 64 + colOff]);
#pragma unroll
            for (int mi = 0; mi < 2; ++mi)
#pragma unroll
                for (int ni = 0; ni < 4; ++ni)
                    acc[mi][ni] = MFMA16(af[mi], bfr[ni], acc[mi][ni]);
        }
        __syncthreads();
    }

    int m_base = m0 + wr * 32, n_base = n0 + wc * 64;
#pragma unroll
    for (int mi = 0; mi < 2; ++mi) {
#pragma unroll
        for (int ni = 0; ni < 4; ++ni) {
            f32x4 v = acc[mi][ni];
            int gn = n_base + ni * 16 + lr;
            int hkv = gn >> 7, d = gn & 127;
            if (isK) {
                int p = d >> 1;
                bool ev = ((d & 1) == 0);
#pragma unroll
                for (int r = 0; r < 4; ++r) {
                    int gm = m_base + mi * 16 + lg * 4 + r;
                    int s = gm & 2047;
                    float cc = cosb[s * 64 + p];
                    float ss = sinb[s * 64 + p];
                    float oth = __shfl_xor(v[r], 1);
                    float rv = ev ? (v[r] * cc - oth * ss) : (oth * ss + v[r] * cc);
                    int bb = gm >> 11;
                    Kt[((size_t)(bb * 4 + hkv) * 2048 + s) * 128 + d] = (bf16)rv;
                }
            } else {
                int gm0 = m_base + mi * 16 + lg * 4;
                int bb = gm0 >> 11, s = gm0 & 2047;
                bf16x4 hh;
#pragma unroll
                for (int r = 0; r < 4; ++r) hh[r] = (bf16)v[r];
                *reinterpret_cast<bf16x4*>(
                    Vt + ((size_t)(bb * 4 + hkv) * 128 + d) * 2048 + s) = hh;
            }
        }
    }
}

// ---------------------------------------------------------------------------
// Output projection, wide-N tiles: 64(M) x 256(N), grid (8,64).
// ---------------------------------------------------------------------------
__global__ __launch_bounds__(256) void gemm_o(
    const bf16* __restrict__ Ain, const bf16* __restrict__ Bt,
    float* __restrict__ Cout, int Nn, int Kk) {
    __shared__ bf16 As[64 * 64];
    __shared__ bf16 Bs[256 * 64];
    int tid = threadIdx.x;
    int lane = tid & 63, wid = tid >> 6;
    int lr = lane & 15, lg = lane >> 4;
    int m0 = blockIdx.y * 64, n0 = blockIdx.x * 256;

    int srow = lane >> 3;
    int scol = ((lane & 7) ^ srow) << 3;
    const bf16* Bbase = Bt + (size_t)(n0 + wid * 64 + srow) * Kk + scol;
    const bf16* Abase = Ain + (size_t)(m0 + wid * 16 + srow) * Kk + scol;

    int fragBr = wid * 64 + lr;
    int swz = lr & 7;

    f32x4 acc[4][4] = {};

    const int nk = Kk >> 6;
    for (int kt = 0; kt < nk; ++kt) {
        int k0 = kt << 6;
#pragma unroll
        for (int i = 0; i < 2; ++i)
            GLOAD_LDS16(Abase + (size_t)(i * 8) * Kk + k0,
                        &As[(wid * 2 + i) * 512]);
#pragma unroll
        for (int i = 0; i < 8; ++i)
            GLOAD_LDS16(Bbase + (size_t)(i * 8) * Kk + k0,
                        &Bs[(wid * 8 + i) * 512]);
        __syncthreads();
#pragma unroll
        for (int kk = 0; kk < 2; ++kk) {
            int colOff = ((((kk << 2) | lg) ^ swz) << 3);
            bf16x8 af[4], bfr[4];
#pragma unroll
            for (int mi = 0; mi < 4; ++mi)
                af[mi] = *reinterpret_cast<const bf16x8*>(
                    &As[(mi * 16 + lr) * 64 + colOff]);
#pragma unroll
            for (int ni = 0; ni < 4; ++ni)
                bfr[ni] = *reinterpret_cast<const bf16x8*>(
                    &Bs[(fragBr + ni * 16) * 64 + colOff]);
#pragma unroll
            for (int mi = 0; mi < 4; ++mi)
#pragma unroll
                for (int ni = 0; ni < 4; ++ni)
                    acc[mi][ni] = MFMA16(af[mi], bfr[ni], acc[mi][ni]);
        }
        __syncthreads();
    }

    int n_base = n0 + wid * 64;
#pragma unroll
    for (int mi = 0; mi < 4; ++mi)
#pragma unroll
        for (int ni = 0; ni < 4; ++ni) {
            f32x4 v = acc[mi][ni];
            int gn = n_base + ni * 16 + lr;
#pragma unroll
            for (int r = 0; r < 4; ++r)
                Cout[(size_t)(m0 + mi * 16 + lg * 4 + r) * Nn + gn] = v[r];
        }
}

// ---------------------------------------------------------------------------
// Causal flash attention, GQA, swapped-operand, KBLK=128 (halved barriers
// and softmax overhead per KV element). Round-11 math, XCD-aware 1D grid
// (bid&7 = b*4+hkv pins each 512KB K/V set to one XCD L2; round-19 win on
// FETCH). Wave = 16 q-rows, q-tile 64/block; diagonal tile may idle <=2
// waves (bounded, unlike round-18). full = q0-s0 >= 127.
// ---------------------------------------------------------------------------
__global__ __launch_bounds__(256) void attn_kernel(
    const bf16* __restrict__ Qp, const bf16* __restrict__ Kt,
    const bf16* __restrict__ Vt, bf16* __restrict__ Ao) {
    const int S = 2048, H = 16, HKV = 4, HD = 128;
    __shared__ bf16 Klds[128][136];
    __shared__ bf16 Vlds[128][136];

    int tid = threadIdx.x, lane = tid & 63, wid = tid >> 6;
    int lr = lane & 15, lg = lane >> 4;
    int f = blockIdx.x;
    int xcd = f & 7, idx = f >> 3;
    int b = xcd >> 2, hkv = xcd & 3;
    int h = hkv * 4 + (idx & 3);
    int qt = 31 - (idx >> 2);
    int q0 = qt * 64 + wid * 16;
    int qrow = q0 + lr;

    const bf16* Kbase = Kt + (size_t)(b * HKV + hkv) * S * HD;
    const bf16* Vbase = Vt + (size_t)(b * HKV + hkv) * HD * S;

    bf16x8 qf[4];
    {
        const bf16* qb = Qp + ((size_t)(b * S + qrow) * H + h) * HD;
#pragma unroll
        for (int ks = 0; ks < 4; ++ks)
            qf[ks] = *reinterpret_cast<const bf16x8*>(qb + ks * 32 + lg * 8);
    }

    f32x4 O[8] = {};
    float m_run = -3e38f, l_run = 0.f;
    int src0 = ((lane >> 4) & 1) * 32 + lr;
    int src1 = src0 + 16;
    bool h1 = (lg >> 1) != 0;

    int nkb = ((qt * 64 + 63) >> 7) + 1;
    for (int kb = 0; kb < nkb; ++kb) {
        int s0 = kb << 7;
        // ---- stage K (128x128) and V (128x128): 2048 slots each ----
        bf16x8 kreg[8], vreg[8];
#pragma unroll
        for (int i = 0; i < 8; ++i) {
            int slot = tid + i * 256;
            int row = slot >> 4, c8 = (slot & 15) << 3;
            kreg[i] = *reinterpret_cast<const bf16x8*>(
                Kbase + (size_t)(s0 + row) * HD + c8);
            vreg[i] = *reinterpret_cast<const bf16x8*>(
                Vbase + (size_t)row * S + s0 + c8);
        }
#pragma unroll
        for (int i = 0; i < 8; ++i) {
            int slot = tid + i * 256;
            int row = slot >> 4, c8 = (slot & 15) << 3;
            *reinterpret_cast<bf16x8*>(&Klds[row][c8]) = kreg[i];
            *reinterpret_cast<bf16x8*>(&Vlds[row][c8]) = vreg[i];
        }
        __syncthreads();

        bool act = (s0 <= q0 + 15);
        bool full = (q0 - s0 >= 127);
        if (act) {
            float p[8][4];
            __builtin_amdgcn_s_setprio(1);
#pragma unroll
            for (int nt = 0; nt < 8; ++nt) {
                f32x4 sc = {};
#pragma unroll
                for (int ks = 0; ks < 4; ++ks) {
                    bf16x8 kf = *reinterpret_cast<const bf16x8*>(
                        &Klds[nt * 16 + lr][ks * 32 + lg * 8]);
                    sc = MFMA16(kf, qf[ks], sc);
                }
                if (!full) {
                    int sa = s0 + nt * 16 + lg * 4;
#pragma unroll
                    for (int r = 0; r < 4; ++r)
                        p[nt][r] = (sa + r <= qrow) ? sc[r] : -1e30f;
                } else {
#pragma unroll
                    for (int r = 0; r < 4; ++r) p[nt][r] = sc[r];
                }
            }
            __builtin_amdgcn_s_setprio(0);

            float mx = p[0][0];
#pragma unroll
            for (int nt = 0; nt < 8; ++nt)
#pragma unroll
                for (int r = 0; r < 4; ++r) mx = fmaxf(mx, p[nt][r]);
            mx = fmaxf(mx, __shfl_xor(mx, 16));
            mx = fmaxf(mx, __shfl_xor(mx, 32));
            float mnew = fmaxf(m_run, mx);
            float al = exp2f(m_run - mnew);
            m_run = mnew;
            float rs = 0.f;
#pragma unroll
            for (int nt = 0; nt < 8; ++nt)
#pragma unroll
                for (int r = 0; r < 4; ++r) {
                    p[nt][r] = exp2f(p[nt][r] - mnew);
                    rs += p[nt][r];
                }
            rs += __shfl_xor(rs, 16);
            rs += __shfl_xor(rs, 32);
            l_run = l_run * al + rs;

            // ---- pack + redistribute (verified permutation, x2) ----
            unsigned pkA[8], pkB[8], eA[8], eB[8], oA[8], oB[8];
#pragma unroll
            for (int nt = 0; nt < 8; ++nt) {
                pkA[nt] = pack2(p[nt][0], p[nt][1]);
                pkB[nt] = pack2(p[nt][2], p[nt][3]);
            }
#pragma unroll
            for (int nt = 0; nt < 8; ++nt) {
                eA[nt] = __shfl(pkA[nt], src0);
                eB[nt] = __shfl(pkB[nt], src0);
                oA[nt] = __shfl(pkA[nt], src1);
                oB[nt] = __shfl(pkB[nt], src1);
            }
            union U { unsigned u[4]; bf16x8 v; } P0, P1, P2, P3;
            P0.u[0] = h1 ? eA[1] : eA[0]; P0.u[1] = h1 ? eB[1] : eB[0];
            P0.u[2] = h1 ? oA[1] : oA[0]; P0.u[3] = h1 ? oB[1] : oB[0];
            P1.u[0] = h1 ? eA[3] : eA[2]; P1.u[1] = h1 ? eB[3] : eB[2];
            P1.u[2] = h1 ? oA[3] : oA[2]; P1.u[3] = h1 ? oB[3] : oB[2];
            P2.u[0] = h1 ? eA[5] : eA[4]; P2.u[1] = h1 ? eB[5] : eB[4];
            P2.u[2] = h1 ? oA[5] : oA[4]; P2.u[3] = h1 ? oB[5] : oB[4];
            P3.u[0] = h1 ? eA[7] : eA[6]; P3.u[1] = h1 ? eB[7] : eB[6];
            P3.u[2] = h1 ? oA[7] : oA[6]; P3.u[3] = h1 ? oB[7] : oB[6];

#pragma unroll
            for (int d2 = 0; d2 < 8; ++d2)
#pragma unroll
                for (int r = 0; r < 4; ++r) O[d2][r] *= al;
            __builtin_amdgcn_s_setprio(1);
#pragma unroll
            for (int d2 = 0; d2 < 8; ++d2) {
                bf16x8 vf0 = *reinterpret_cast<const bf16x8*>(
                    &Vlds[d2 * 16 + lr][lg * 8]);
                bf16x8 vf1 = *reinterpret_cast<const bf16x8*>(
                    &Vlds[d2 * 16 + lr][32 + lg * 8]);
                bf16x8 vf2 = *reinterpret_cast<const bf16x8*>(
                    &Vlds[d2 * 16 + lr][64 + lg * 8]);
                bf16x8 vf3 = *reinterpret_cast<const bf16x8*>(
                    &Vlds[d2 * 16 + lr][96 + lg * 8]);
                O[d2] = MFMA16(vf0, P0.v, O[d2]);
                O[d2] = MFMA16(vf1, P1.v, O[d2]);
                O[d2] = MFMA16(vf2, P2.v, O[d2]);
                O[d2] = MFMA16(vf3, P3.v, O[d2]);
            }
            __builtin_amdgcn_s_setprio(0);
        }
        __syncthreads();
    }

    float inv = 1.0f / l_run;
    const size_t obase = ((size_t)(b * S + qrow) * H + h) * HD;
#pragma unroll
    for (int d2 = 0; d2 < 8; ++d2) {
        bf16x4 st;
#pragma unroll
        for (int r = 0; r < 4; ++r) st[r] = (bf16)(O[d2][r] * inv);
        *reinterpret_cast<bf16x4*>(const_cast<bf16*>(Ao) + obase + d2 * 16 +
                                   lg * 4) = st;
    }
}

// ---------------------------------------------------------------------------
extern "C" void kernel_launch(void* const* d_in, const int* in_sizes, int n_in,
                              void* d_out, int out_size, void* d_ws,
                              size_t ws_size, hipStream_t stream) {
    const float* q = (const float*)d_in[0];
    const float* k = (const float*)d_in[1];
    const float* v = (const float*)d_in[2];
    // d_in[3] = mask (causal tril; handled analytically)
    const float* fc = (const float*)d_in[4];
    const float* fs = (const float*)d_in[5];
    const float* Wq = (const float*)d_in[6];
    const float* Wk = (const float*)d_in[7];
    const float* Wv = (const float*)d_in[8];
    const float* Wo = (const float*)d_in[9];

    char* ws = (char*)d_ws;
    bf16* Wq_t = (bf16*)(ws + 0);          //  8,388,608 B
    bf16* Wk_t = (bf16*)(ws + 8388608);    //  2,097,152
    bf16* Wv_t = (bf16*)(ws + 10485760);   //  2,097,152
    bf16* Wo_t = (bf16*)(ws + 12582912);   //  8,388,608
    bf16* Qp   = (bf16*)(ws + 20971520);   // 16,777,216
    bf16* Kt   = (bf16*)(ws + 37748736);   //  4,194,304
    bf16* Vt   = (bf16*)(ws + 41943040);   //  4,194,304
    bf16* Ao   = (bf16*)(ws + 46137344);   // 16,777,216  (end 62,914,560)

    transpose_cvt4<<<dim3(64, 64, 4), dim3(32, 8), 0, stream>>>(
        Wq, Wo, Wk, Wv, Wq_t, Wo_t, Wk_t, Wv_t);

    // 1/sqrt(128) * log2(e)  (attention softmax runs in exp2 domain)
    const float qscale = 0.08838834764831845f * 1.4426950408889634f;

    gemm_q<<<dim3(8, 64), 256, 0, stream>>>(q, Wq_t, Qp, fc, fs, qscale);
    gemm_kv<<<dim3(4, 64, 2), 256, 0, stream>>>(k, v, Wk_t, Wv_t, Kt, Vt, fc,
                                                fs);

    // XCD-aware 1D grid: 1024 blocks, bid&7 = b*4+hkv; KBLK=128
    attn_kernel<<<dim3(1024), 256, 0, stream>>>(Qp, Kt, Vt, Ao);

    gemm_o<<<dim3(8, 64), 256, 0, stream>>>(Ao, Wo_t, (float*)d_out, 2048,
                                            2048);
}

// Round 21
// 233.224 us; speedup vs baseline: 1.0451x; 1.0451x over previous
//
#include <hip/hip_runtime.h>

typedef __bf16 bf16;
typedef __attribute__((ext_vector_type(8))) __bf16 bf16x8;
typedef __attribute__((ext_vector_type(4))) __bf16 bf16x4;
typedef __attribute__((ext_vector_type(4))) float f32x4;

#define MFMA16(a, b, c) __builtin_amdgcn_mfma_f32_16x16x32_bf16((a), (b), (c), 0, 0, 0)

typedef __attribute__((address_space(1))) const void* gas_t;
typedef __attribute__((address_space(3))) void* las_t;
#define GLOAD_LDS16(g, l) \
    __builtin_amdgcn_global_load_lds((gas_t)(g), (las_t)(l), 16, 0, 0)

__device__ __forceinline__ unsigned pack2(float a, float b) {
    unsigned short ua = __builtin_bit_cast(unsigned short, (bf16)a);
    unsigned short ub = __builtin_bit_cast(unsigned short, (bf16)b);
    return ((unsigned)ub << 16) | (unsigned)ua;
}

// ---------------------------------------------------------------------------
// Fused transpose+cvt of all four weights: W[K][N] fp32 -> Wt[N][K] bf16.
// ---------------------------------------------------------------------------
__global__ void transpose_cvt4(const float* __restrict__ Wq,
                               const float* __restrict__ Wo,
                               const float* __restrict__ Wk,
                               const float* __restrict__ Wv,
                               bf16* __restrict__ WqT, bf16* __restrict__ WoT,
                               bf16* __restrict__ WkT, bf16* __restrict__ WvT) {
    __shared__ bf16 tile[32][33];
    int z = blockIdx.z;
    const float* W = (z == 0) ? Wq : (z == 1) ? Wo : (z == 2) ? Wk : Wv;
    bf16* Wt = (z == 0) ? WqT : (z == 1) ? WoT : (z == 2) ? WkT : WvT;
    int N = (z < 2) ? 2048 : 512;
    const int K = 2048;
    int n0 = blockIdx.x * 32;
    if (n0 >= N) return;
    int k0 = blockIdx.y * 32;
    int tx = threadIdx.x, ty = threadIdx.y;  // 32 x 8
#pragma unroll
    for (int j = 0; j < 4; ++j)
        tile[ty + j * 8][tx] = (bf16)W[(size_t)(k0 + ty + j * 8) * N + n0 + tx];
    __syncthreads();
#pragma unroll
    for (int j = 0; j < 4; ++j)
        Wt[(size_t)(n0 + ty + j * 8) * K + k0 + tx] = tile[tx][ty + j * 8];
}

// ---------------------------------------------------------------------------
// Q projection, wide-N tiles: 64(M) x 256(N), BK=64, grid (8,64).
// ---------------------------------------------------------------------------
__global__ __launch_bounds__(256) void gemm_q(
    const float* __restrict__ A, const bf16* __restrict__ Bt,
    bf16* __restrict__ Qp, const float* __restrict__ cosb,
    const float* __restrict__ sinb, float qscale) {
    const int Kk = 2048, Nn = 2048;
    __shared__ bf16 As[64 * 64];
    __shared__ bf16 Bs[256 * 64];
    int tid = threadIdx.x;
    int lane = tid & 63, wid = tid >> 6;
    int lr = lane & 15, lg = lane >> 4;
    int m0 = blockIdx.y * 64, n0 = blockIdx.x * 256;

    int srow = lane >> 3;
    int scol = ((lane & 7) ^ srow) << 3;
    const bf16* Bbase = Bt + (size_t)(n0 + wid * 64 + srow) * Kk + scol;

    int fragBr = wid * 64 + lr;
    int swz = lr & 7;

    f32x4 acc[4][4] = {};

    for (int kt = 0; kt < 32; ++kt) {
        int k0 = kt << 6;
#pragma unroll
        for (int i = 0; i < 4; ++i) {
            int slot = tid + i * 256;
            int row = slot >> 4, c4 = (slot & 15) << 2;
            f32x4 v = *reinterpret_cast<const f32x4*>(
                A + (size_t)(m0 + row) * Kk + k0 + c4);
            bf16x4 h;
            h[0] = (bf16)v[0]; h[1] = (bf16)v[1];
            h[2] = (bf16)v[2]; h[3] = (bf16)v[3];
            int blk = (c4 >> 3) ^ (row & 7);
            *reinterpret_cast<bf16x4*>(&As[row * 64 + (blk << 3) + (c4 & 7)]) = h;
        }
#pragma unroll
        for (int i = 0; i < 8; ++i)
            GLOAD_LDS16(Bbase + (size_t)(i * 8) * Kk + k0,
                        &Bs[(wid * 8 + i) * 512]);
        __syncthreads();
#pragma unroll
        for (int kk = 0; kk < 2; ++kk) {
            int colOff = ((((kk << 2) | lg) ^ swz) << 3);
            bf16x8 af[4], bfr[4];
#pragma unroll
            for (int mi = 0; mi < 4; ++mi)
                af[mi] = *reinterpret_cast<const bf16x8*>(
                    &As[(mi * 16 + lr) * 64 + colOff]);
#pragma unroll
            for (int ni = 0; ni < 4; ++ni)
                bfr[ni] = *reinterpret_cast<const bf16x8*>(
                    &Bs[(fragBr + ni * 16) * 64 + colOff]);
#pragma unroll
            for (int mi = 0; mi < 4; ++mi)
#pragma unroll
                for (int ni = 0; ni < 4; ++ni)
                    acc[mi][ni] = MFMA16(af[mi], bfr[ni], acc[mi][ni]);
        }
        __syncthreads();
    }

    int n_base = n0 + wid * 64;
#pragma unroll
    for (int mi = 0; mi < 4; ++mi) {
#pragma unroll
        for (int ni = 0; ni < 4; ++ni) {
            f32x4 v = acc[mi][ni];
            int gn = n_base + ni * 16 + lr;
            int d = gn & 127, p = d >> 1;
            bool ev = ((d & 1) == 0);
#pragma unroll
            for (int r = 0; r < 4; ++r) {
                int gm = m0 + mi * 16 + lg * 4 + r;
                int s = gm & 2047;
                float cc = cosb[s * 64 + p];
                float ss = sinb[s * 64 + p];
                float oth = __shfl_xor(v[r], 1);
                v[r] = (ev ? (v[r] * cc - oth * ss)
                           : (oth * ss + v[r] * cc)) * qscale;
            }
#pragma unroll
            for (int r = 0; r < 4; ++r)
                Qp[(size_t)(m0 + mi * 16 + lg * 4 + r) * Nn + gn] =
                    (bf16)v[r];
        }
    }
}

// ---------------------------------------------------------------------------
// Fused K+V projection, M-split tiles: 64(M) x 128(N). grid (4, 64, 2).
// ---------------------------------------------------------------------------
__global__ __launch_bounds__(256) void gemm_kv(
    const float* __restrict__ kin, const float* __restrict__ vin,
    const bf16* __restrict__ WkT, const bf16* __restrict__ WvT,
    bf16* __restrict__ Kt, bf16* __restrict__ Vt,
    const float* __restrict__ cosb, const float* __restrict__ sinb) {
    const int Kk = 2048;
    __shared__ bf16 As[64 * 64];
    __shared__ bf16 Bs[128 * 64];
    bool isK = (blockIdx.z == 0);
    const float* A = isK ? kin : vin;
    const bf16* Bt = isK ? WkT : WvT;

    int tid = threadIdx.x;
    int lane = tid & 63, wid = tid >> 6;
    int lr = lane & 15, lg = lane >> 4;
    int m0 = blockIdx.y * 64, n0 = blockIdx.x * 128;
    int wr = wid >> 1, wc = wid & 1;

    int srow = lane >> 3;
    int scol = ((lane & 7) ^ srow) << 3;
    const bf16* Bbase = Bt + (size_t)(n0 + wid * 32 + srow) * Kk + scol;

    int fragAr = wr * 32 + lr;
    int fragBr = wc * 64 + lr;
    int swz = lr & 7;

    f32x4 acc[2][4] = {};

    for (int kt = 0; kt < 32; ++kt) {
        int k0 = kt << 6;
#pragma unroll
        for (int i = 0; i < 4; ++i) {
            int slot = tid + i * 256;
            int row = slot >> 4, c4 = (slot & 15) << 2;
            f32x4 v = *reinterpret_cast<const f32x4*>(
                A + (size_t)(m0 + row) * Kk + k0 + c4);
            bf16x4 h;
            h[0] = (bf16)v[0]; h[1] = (bf16)v[1];
            h[2] = (bf16)v[2]; h[3] = (bf16)v[3];
            int blk = (c4 >> 3) ^ (row & 7);
            *reinterpret_cast<bf16x4*>(&As[row * 64 + (blk << 3) + (c4 & 7)]) = h;
        }
#pragma unroll
        for (int i = 0; i < 4; ++i)
            GLOAD_LDS16(Bbase + (size_t)(i * 8) * Kk + k0,
                        &Bs[(wid * 4 + i) * 512]);
        __syncthreads();
#pragma unroll
        for (int kk = 0; kk < 2; ++kk) {
            int colOff = ((((kk << 2) | lg) ^ swz) << 3);
            bf16x8 af[2], bfr[4];
#pragma unroll
            for (int mi = 0; mi < 2; ++mi)
                af[mi] = *reinterpret_cast<const bf16x8*>(
                    &As[(fragAr + mi * 16) * 64 + colOff]);
#pragma unroll
            for (int ni = 0; ni < 4; ++ni)
                bfr[ni] = *reinterpret_cast<const bf16x8*>(
                    &Bs[(fragBr + ni * 16) * 64 + colOff]);
#pragma unroll
            for (int mi = 0; mi < 2; ++mi)
#pragma unroll
                for (int ni = 0; ni < 4; ++ni)
                    acc[mi][ni] = MFMA16(af[mi], bfr[ni], acc[mi][ni]);
        }
        __syncthreads();
    }

    int m_base = m0 + wr * 32, n_base = n0 + wc * 64;
#pragma unroll
    for (int mi = 0; mi < 2; ++mi) {
#pragma unroll
        for (int ni = 0; ni < 4; ++ni) {
            f32x4 v = acc[mi][ni];
            int gn = n_base + ni * 16 + lr;
            int hkv = gn >> 7, d = gn & 127;
            if (isK) {
                int p = d >> 1;
                bool ev = ((d & 1) == 0);
#pragma unroll
                for (int r = 0; r < 4; ++r) {
                    int gm = m_base + mi * 16 + lg * 4 + r;
                    int s = gm & 2047;
                    float cc = cosb[s * 64 + p];
                    float ss = sinb[s * 64 + p];
                    float oth = __shfl_xor(v[r], 1);
                    float rv = ev ? (v[r] * cc - oth * ss) : (oth * ss + v[r] * cc);
                    int bb = gm >> 11;
                    Kt[((size_t)(bb * 4 + hkv) * 2048 + s) * 128 + d] = (bf16)rv;
                }
            } else {
                int gm0 = m_base + mi * 16 + lg * 4;
                int bb = gm0 >> 11, s = gm0 & 2047;
                bf16x4 hh;
#pragma unroll
                for (int r = 0; r < 4; ++r) hh[r] = (bf16)v[r];
                *reinterpret_cast<bf16x4*>(
                    Vt + ((size_t)(bb * 4 + hkv) * 128 + d) * 2048 + s) = hh;
            }
        }
    }
}

// ---------------------------------------------------------------------------
// Output projection, wide-N tiles: 64(M) x 256(N), grid (8,64).
// ---------------------------------------------------------------------------
__global__ __launch_bounds__(256) void gemm_o(
    const bf16* __restrict__ Ain, const bf16* __restrict__ Bt,
    float* __restrict__ Cout, int Nn, int Kk) {
    __shared__ bf16 As[64 * 64];
    __shared__ bf16 Bs[256 * 64];
    int tid = threadIdx.x;
    int lane = tid & 63, wid = tid >> 6;
    int lr = lane & 15, lg = lane >> 4;
    int m0 = blockIdx.y * 64, n0 = blockIdx.x * 256;

    int srow = lane >> 3;
    int scol = ((lane & 7) ^ srow) << 3;
    const bf16* Bbase = Bt + (size_t)(n0 + wid * 64 + srow) * Kk + scol;
    const bf16* Abase = Ain + (size_t)(m0 + wid * 16 + srow) * Kk + scol;

    int fragBr = wid * 64 + lr;
    int swz = lr & 7;

    f32x4 acc[4][4] = {};

    const int nk = Kk >> 6;
    for (int kt = 0; kt < nk; ++kt) {
        int k0 = kt << 6;
#pragma unroll
        for (int i = 0; i < 2; ++i)
            GLOAD_LDS16(Abase + (size_t)(i * 8) * Kk + k0,
                        &As[(wid * 2 + i) * 512]);
#pragma unroll
        for (int i = 0; i < 8; ++i)
            GLOAD_LDS16(Bbase + (size_t)(i * 8) * Kk + k0,
                        &Bs[(wid * 8 + i) * 512]);
        __syncthreads();
#pragma unroll
        for (int kk = 0; kk < 2; ++kk) {
            int colOff = ((((kk << 2) | lg) ^ swz) << 3);
            bf16x8 af[4], bfr[4];
#pragma unroll
            for (int mi = 0; mi < 4; ++mi)
                af[mi] = *reinterpret_cast<const bf16x8*>(
                    &As[(mi * 16 + lr) * 64 + colOff]);
#pragma unroll
            for (int ni = 0; ni < 4; ++ni)
                bfr[ni] = *reinterpret_cast<const bf16x8*>(
                    &Bs[(fragBr + ni * 16) * 64 + colOff]);
#pragma unroll
            for (int mi = 0; mi < 4; ++mi)
#pragma unroll
                for (int ni = 0; ni < 4; ++ni)
                    acc[mi][ni] = MFMA16(af[mi], bfr[ni], acc[mi][ni]);
        }
        __syncthreads();
    }

    int n_base = n0 + wid * 64;
#pragma unroll
    for (int mi = 0; mi < 4; ++mi)
#pragma unroll
        for (int ni = 0; ni < 4; ++ni) {
            f32x4 v = acc[mi][ni];
            int gn = n_base + ni * 16 + lr;
#pragma unroll
            for (int r = 0; r < 4; ++r)
                Cout[(size_t)(m0 + mi * 16 + lg * 4 + r) * Nn + gn] = v[r];
        }
}

// ---------------------------------------------------------------------------
// Causal flash attention, GQA, swapped-operand — round-11 kernel body
// (best measured 85.7-87.1 us) + T1 XCD-aware 1D grid (round-19:
// FETCH 26.8 -> 12.4 MB): bid&7 = xcd = b*4+hkv; idx = bid>>3 gives
// h = hkv*4 + (idx&3), qt = 31 - (idx>>2) (LPT per XCD).
// Wave = 16 q-rows; q-tile 64; KBLK 64; exp2 softmax; T5 setprio.
// ---------------------------------------------------------------------------
__global__ __launch_bounds__(256) void attn_kernel(
    const bf16* __restrict__ Qp, const bf16* __restrict__ Kt,
    const bf16* __restrict__ Vt, bf16* __restrict__ Ao) {
    const int S = 2048, H = 16, HKV = 4, HD = 128;
    __shared__ bf16 Klds[64][136];
    __shared__ bf16 Vlds[128][72];

    int tid = threadIdx.x, lane = tid & 63, wid = tid >> 6;
    int lr = lane & 15, lg = lane >> 4;
    int f = blockIdx.x;
    int xcd = f & 7, idx = f >> 3;
    int b = xcd >> 2, hkv = xcd & 3;
    int h = hkv * 4 + (idx & 3);
    int qt = 31 - (idx >> 2);
    int q0 = qt * 64 + wid * 16;
    int qrow = q0 + lr;

    const bf16* Kbase = Kt + (size_t)(b * HKV + hkv) * S * HD;
    const bf16* Vbase = Vt + (size_t)(b * HKV + hkv) * HD * S;

    bf16x8 qf[4];
    {
        const bf16* qb = Qp + ((size_t)(b * S + qrow) * H + h) * HD;
#pragma unroll
        for (int ks = 0; ks < 4; ++ks)
            qf[ks] = *reinterpret_cast<const bf16x8*>(qb + ks * 32 + lg * 8);
    }

    f32x4 O[8] = {};
    float m_run = -3e38f, l_run = 0.f;
    int src0 = ((lane >> 4) & 1) * 32 + lr;
    int src1 = src0 + 16;
    bool h1 = (lg >> 1) != 0;

    for (int kb = 0; kb <= qt; ++kb) {
        int s0 = kb * 64;
        bf16x8 kreg[4], vreg[4];
#pragma unroll
        for (int i = 0; i < 4; ++i) {
            int slot = tid + i * 256;
            int krow = slot >> 4, kc = (slot & 15) << 3;
            kreg[i] = *reinterpret_cast<const bf16x8*>(
                Kbase + (size_t)(s0 + krow) * HD + kc);
            int vrow = slot >> 3, vc = (slot & 7) << 3;
            vreg[i] = *reinterpret_cast<const bf16x8*>(
                Vbase + (size_t)vrow * S + s0 + vc);
        }
#pragma unroll
        for (int i = 0; i < 4; ++i) {
            int slot = tid + i * 256;
            int krow = slot >> 4, kc = (slot & 15) << 3;
            *reinterpret_cast<bf16x8*>(&Klds[krow][kc]) = kreg[i];
            int vrow = slot >> 3, vc = (slot & 7) << 3;
            *reinterpret_cast<bf16x8*>(&Vlds[vrow][vc]) = vreg[i];
        }
        __syncthreads();

        float p[4][4];
        __builtin_amdgcn_s_setprio(1);
#pragma unroll
        for (int nt = 0; nt < 4; ++nt) {
            f32x4 sc = {};
#pragma unroll
            for (int ks = 0; ks < 4; ++ks) {
                bf16x8 kf = *reinterpret_cast<const bf16x8*>(
                    &Klds[nt * 16 + lr][ks * 32 + lg * 8]);
                sc = MFMA16(kf, qf[ks], sc);
            }
            if (kb == qt) {
                int sa = s0 + nt * 16 + lg * 4;
#pragma unroll
                for (int r = 0; r < 4; ++r)
                    p[nt][r] = (sa + r <= qrow) ? sc[r] : -1e30f;
            } else {
#pragma unroll
                for (int r = 0; r < 4; ++r) p[nt][r] = sc[r];
            }
        }
        __builtin_amdgcn_s_setprio(0);

        float mx = p[0][0];
#pragma unroll
        for (int nt = 0; nt < 4; ++nt)
#pragma unroll
            for (int r = 0; r < 4; ++r) mx = fmaxf(mx, p[nt][r]);
        mx = fmaxf(mx, __shfl_xor(mx, 16));
        mx = fmaxf(mx, __shfl_xor(mx, 32));
        float mnew = fmaxf(m_run, mx);
        float al = exp2f(m_run - mnew);
        m_run = mnew;
        float rs = 0.f;
#pragma unroll
        for (int nt = 0; nt < 4; ++nt)
#pragma unroll
            for (int r = 0; r < 4; ++r) {
                p[nt][r] = exp2f(p[nt][r] - mnew);
                rs += p[nt][r];
            }
        rs += __shfl_xor(rs, 16);
        rs += __shfl_xor(rs, 32);
        l_run = l_run * al + rs;

        unsigned pk00 = pack2(p[0][0], p[0][1]), pk01 = pack2(p[0][2], p[0][3]);
        unsigned pk10 = pack2(p[1][0], p[1][1]), pk11 = pack2(p[1][2], p[1][3]);
        unsigned pk20 = pack2(p[2][0], p[2][1]), pk21 = pack2(p[2][2], p[2][3]);
        unsigned pk30 = pack2(p[3][0], p[3][1]), pk31 = pack2(p[3][2], p[3][3]);
        unsigned e00 = __shfl(pk00, src0), e01 = __shfl(pk01, src0);
        unsigned e10 = __shfl(pk10, src0), e11 = __shfl(pk11, src0);
        unsigned e20 = __shfl(pk20, src0), e21 = __shfl(pk21, src0);
        unsigned e30 = __shfl(pk30, src0), e31 = __shfl(pk31, src0);
        unsigned o00 = __shfl(pk00, src1), o01 = __shfl(pk01, src1);
        unsigned o10 = __shfl(pk10, src1), o11 = __shfl(pk11, src1);
        unsigned o20 = __shfl(pk20, src1), o21 = __shfl(pk21, src1);
        unsigned o30 = __shfl(pk30, src1), o31 = __shfl(pk31, src1);
        union U { unsigned u[4]; bf16x8 v; } P0, P1;
        P0.u[0] = h1 ? e10 : e00;
        P0.u[1] = h1 ? e11 : e01;
        P0.u[2] = h1 ? o10 : o00;
        P0.u[3] = h1 ? o11 : o01;
        P1.u[0] = h1 ? e30 : e20;
        P1.u[1] = h1 ? e31 : e21;
        P1.u[2] = h1 ? o30 : o20;
        P1.u[3] = h1 ? o31 : o21;

#pragma unroll
        for (int d2 = 0; d2 < 8; ++d2)
#pragma unroll
            for (int r = 0; r < 4; ++r) O[d2][r] *= al;
        __builtin_amdgcn_s_setprio(1);
#pragma unroll
        for (int d2 = 0; d2 < 8; ++d2) {
            bf16x8 vf0 =
                *reinterpret_cast<const bf16x8*>(&Vlds[d2 * 16 + lr][lg * 8]);
            bf16x8 vf1 = *reinterpret_cast<const bf16x8*>(
                &Vlds[d2 * 16 + lr][32 + lg * 8]);
            O[d2] = MFMA16(vf0, P0.v, O[d2]);
            O[d2] = MFMA16(vf1, P1.v, O[d2]);
        }
        __builtin_amdgcn_s_setprio(0);
        __syncthreads();
    }

    float inv = 1.0f / l_run;
    const size_t obase = ((size_t)(b * S + qrow) * H + h) * HD;
#pragma unroll
    for (int d2 = 0; d2 < 8; ++d2) {
        bf16x4 st;
#pragma unroll
        for (int r = 0; r < 4; ++r) st[r] = (bf16)(O[d2][r] * inv);
        *reinterpret_cast<bf16x4*>(const_cast<bf16*>(Ao) + obase + d2 * 16 +
                                   lg * 4) = st;
    }
}

// ---------------------------------------------------------------------------
extern "C" void kernel_launch(void* const* d_in, const int* in_sizes, int n_in,
                              void* d_out, int out_size, void* d_ws,
                              size_t ws_size, hipStream_t stream) {
    const float* q = (const float*)d_in[0];
    const float* k = (const float*)d_in[1];
    const float* v = (const float*)d_in[2];
    // d_in[3] = mask (causal tril; handled analytically)
    const float* fc = (const float*)d_in[4];
    const float* fs = (const float*)d_in[5];
    const float* Wq = (const float*)d_in[6];
    const float* Wk = (const float*)d_in[7];
    const float* Wv = (const float*)d_in[8];
    const float* Wo = (const float*)d_in[9];

    char* ws = (char*)d_ws;
    bf16* Wq_t = (bf16*)(ws + 0);          //  8,388,608 B
    bf16* Wk_t = (bf16*)(ws + 8388608);    //  2,097,152
    bf16* Wv_t = (bf16*)(ws + 10485760);   //  2,097,152
    bf16* Wo_t = (bf16*)(ws + 12582912);   //  8,388,608
    bf16* Qp   = (bf16*)(ws + 20971520);   // 16,777,216
    bf16* Kt   = (bf16*)(ws + 37748736);   //  4,194,304
    bf16* Vt   = (bf16*)(ws + 41943040);   //  4,194,304
    bf16* Ao   = (bf16*)(ws + 46137344);   // 16,777,216  (end 62,914,560)

    transpose_cvt4<<<dim3(64, 64, 4), dim3(32, 8), 0, stream>>>(
        Wq, Wo, Wk, Wv, Wq_t, Wo_t, Wk_t, Wv_t);

    // 1/sqrt(128) * log2(e)  (attention softmax runs in exp2 domain)
    const float qscale = 0.08838834764831845f * 1.4426950408889634f;

    gemm_q<<<dim3(8, 64), 256, 0, stream>>>(q, Wq_t, Qp, fc, fs, qscale);
    gemm_kv<<<dim3(4, 64, 2), 256, 0, stream>>>(k, v, Wk_t, Wv_t, Kt, Vt, fc,
                                                fs);

    // XCD-aware 1D grid: 1024 blocks, bid&7 = b*4+hkv
    attn_kernel<<<dim3(1024), 256, 0, stream>>>(Qp, Kt, Vt, Ao);

    gemm_o<<<dim3(8, 64), 256, 0, stream>>>(Ao, Wo_t, (float*)d_out, 2048,
                                            2048);
}